// Round 17
// baseline (368.054 us; speedup 1.0000x reference)
//
#include <hip/hip_runtime.h>
#include <hip/hip_bf16.h>
#include <math.h>

using bf16 = __hip_bfloat16;
typedef __attribute__((ext_vector_type(8))) short short8;
typedef __attribute__((ext_vector_type(4))) float f32x4;
typedef unsigned int u32;

// ---------------- problem constants ----------------
constexpr int BB    = 4;
constexpr int Hh    = 112;
constexpr int Ww    = 112;
constexpr int C     = 256;
constexpr int L     = Hh * Ww;        // 12544
constexpr int HEADS = 8;
constexpr int WS    = 7;
constexpr int SHIFT = 3;
constexpr int HID   = 1024;
constexpr int HD    = 32;
constexpr int NWIN  = 49;
constexpr int NW    = 256;
constexpr int BT    = BB * NW;        // 1024 windows
constexpr int M     = BT * NWIN;      // 50176 tokens
constexpr float SCALE = 0.17677669529663687f;
constexpr float EPS   = 1e-5f;

// window-token r -> natural token index. Same map for gather and scatter.
__device__ __forceinline__ int src_row_idx(int r) {
    int b_ = r / NWIN;
    int n  = r - b_ * NWIN;
    int b  = b_ >> 8;
    int w  = b_ & 255;
    int wh = w >> 4, ww = w & 15;
    int i  = n / WS, j = n - i * WS;
    int hp = wh * WS + i, wp = ww * WS + j;
    int h  = hp + SHIFT; if (h >= Hh) h -= Hh;
    int wc = wp + SHIFT; if (wc >= Ww) wc -= Ww;
    return b * L + h * Ww + wc;
}

__device__ __forceinline__ float bf2f(short s) {
    u32 u = ((u32)(unsigned short)s) << 16;
    float f; __builtin_memcpy(&f, &u, 4); return f;
}
__device__ __forceinline__ short f2bfbits(float f) {
    bf16 b = __float2bfloat16(f);
    short s; __builtin_memcpy(&s, &b, 2); return s;
}
__device__ __forceinline__ u32 pack2bf(float lo, float hi) {
    return (u32)(unsigned short)f2bfbits(lo) | ((u32)(unsigned short)f2bfbits(hi) << 16);
}

#define GL2LDS(g, l) __builtin_amdgcn_global_load_lds( \
    (const __attribute__((address_space(1))) u32*)(const void*)(g), \
    (__attribute__((address_space(3))) u32*)(void*)(l), 16, 0, 0)

// ---------------- fused LN (+optional gather) -> bf16 ----------------
__global__ __launch_bounds__(256)
void prep_ln(const float* __restrict__ x, const float* __restrict__ g,
             const float* __restrict__ b, bf16* __restrict__ o, int gather) {
    int wave = threadIdx.x >> 6, lane = threadIdx.x & 63;
    int tok = blockIdx.x * 4 + wave;
    int srow = gather ? src_row_idx(tok) : tok;
    float4 v = *(const float4*)&x[(size_t)srow * C + lane * 4];
    float s  = v.x + v.y + v.z + v.w;
    float s2 = v.x*v.x + v.y*v.y + v.z*v.z + v.w*v.w;
    #pragma unroll
    for (int ofs = 32; ofs > 0; ofs >>= 1) {
        s  += __shfl_xor(s, ofs);
        s2 += __shfl_xor(s2, ofs);
    }
    float m    = s * (1.f / C);
    float rstd = rsqrtf(s2 * (1.f / C) - m * m + EPS);
    float4 gv = *(const float4*)&g[lane * 4];
    float4 bv = *(const float4*)&b[lane * 4];
    uint2 u;
    u.x = pack2bf((v.x - m) * rstd * gv.x + bv.x, (v.y - m) * rstd * gv.y + bv.y);
    u.y = pack2bf((v.z - m) * rstd * gv.z + bv.z, (v.w - m) * rstd * gv.w + bv.w);
    *(uint2*)&o[(size_t)tok * C + lane * 4] = u;
}

// ---------------- f32 -> bf16 weight convert ----------------
__global__ __launch_bounds__(256)
void cvt_w(const float* __restrict__ in, bf16* __restrict__ o, int n4) {
    int i = blockIdx.x * 256 + threadIdx.x;
    if (i >= n4) return;
    float4 v = *(const float4*)&in[(size_t)i * 4];
    bf16 t4[4] = {__float2bfloat16(v.x), __float2bfloat16(v.y),
                  __float2bfloat16(v.z), __float2bfloat16(v.w)};
    *(uint2*)&o[(size_t)i * 4] = *(const uint2*)t4;
}

// ---------------- vote-embed MLP: 64 tokens/block x 4 channel-quarters ----
__global__ __launch_bounds__(256)
void vemb_kernel(const float* __restrict__ vote,
                 const float* __restrict__ w1, const float* __restrict__ b1,
                 const float* __restrict__ w2, const float* __restrict__ b2,
                 bf16* __restrict__ vemb) {
    __shared__ float w2s[256][16];   // reads wave-uniform -> broadcast
    __shared__ float b2s[256];
    __shared__ float w1s[48], b1s[16];
    const int tid = threadIdx.x;
    {   // stage weights once per block (w2 is 16KB, L2-hot)
        const float4* src = (const float4*)(w2 + tid * 16);
        float4* dst = (float4*)&w2s[tid][0];
        dst[0] = src[0]; dst[1] = src[1]; dst[2] = src[2]; dst[3] = src[3];
        b2s[tid] = b2[tid];
        if (tid < 48) w1s[tid] = w1[tid];
        else if (tid < 64) b1s[tid - 48] = b1[tid - 48];
    }
    __syncthreads();

    const int tok = tid & 63;                 // token within block
    const int cq  = tid >> 6;                 // channel quarter 0..3
    const int r   = blockIdx.x * 64 + tok;
    const int srow = src_row_idx(r);
    const float v0 = vote[(size_t)srow * 3];
    const float v1 = vote[(size_t)srow * 3 + 1];
    const float v2 = vote[(size_t)srow * 3 + 2];
    float hid[16];
    #pragma unroll
    for (int o = 0; o < 16; ++o)
        hid[o] = fmaxf(fmaf(w1s[o*3], v0, fmaf(w1s[o*3+1], v1, fmaf(w1s[o*3+2], v2, b1s[o]))), 0.f);

    bf16* orow = vemb + (size_t)r * 256 + cq * 64;
    for (int c0 = 0; c0 < 64; c0 += 8) {
        bf16 t8[8];
        #pragma unroll
        for (int j = 0; j < 8; ++j) {
            const int c = cq * 64 + c0 + j;
            float a = b2s[c];
            #pragma unroll
            for (int o = 0; o < 16; ++o) a = fmaf(hid[o], w2s[c][o], a);
            t8[j] = __float2bfloat16(a);
        }
        *(uint4*)&orow[c0] = *(const uint4*)t8;
    }
}

// ---------------- MFMA GEMM: pure-DMA A+B, XCD-chunked swizzle ----------
enum { MODE_QKV = 0, MODE_PROJ = 1, MODE_FC1 = 2, MODE_FC2 = 3 };

template <int MODE, int NT>
__global__ __launch_bounds__(256)
void mfma_gemm(const bf16* __restrict__ A, const bf16* __restrict__ Wb,
               const float* __restrict__ bias,
               const bf16* __restrict__ vemb, const float* __restrict__ resid,
               void* __restrict__ outp) {
    constexpr int K = (MODE == MODE_FC2) ? 1024 : 256;
    __shared__ __align__(16) char lds[32768];
    char* ldsA = lds;
    char* ldsB = lds + 16384;

    const int tid  = threadIdx.x;
    const int lane = tid & 63;
    const int wid  = tid >> 6;
    const int wr   = wid >> 1, wc = wid & 1;
    const int lrow = lane & 15, lk = lane >> 4;

    const int cpx = gridDim.x >> 3;                   // nwg always %8==0
    const int lg  = (blockIdx.x & 7) * cpx + (blockIdx.x >> 3);
    const int bx  = lg / NT, by = lg % NT;
    const int mBase = bx * 128, nBase = by * 128;

    const int s_sub = tid >> 3;
    const int chunk = tid & 7;
    const int s_dst = (chunk * 16) ^ ((s_sub & 7) << 4);
    const char* bSrc = (const char*)(Wb + (size_t)(nBase + s_sub) * K) + s_dst;
    const char* aSrc = (const char*)(A  + (size_t)(mBase + s_sub) * K) + s_dst;

    f32x4 acc[4][4] = {};

    for (int t = 0; t < K / 64; ++t) {
        if (t) __syncthreads();
        #pragma unroll
        for (int r = 0; r < 4; ++r) {
            GL2LDS(bSrc + (size_t)r * 64 * K + (size_t)t * 128,
                   ldsB + r * 4096 + wid * 1024);
            GL2LDS(aSrc + (size_t)r * 64 * K + (size_t)t * 128,
                   ldsA + r * 4096 + wid * 1024);
        }
        __syncthreads();
        const int sw = (lrow & 7) << 4;
        #pragma unroll
        for (int ks = 0; ks < 2; ++ks) {
            const int kbl = (ks * 64 + lk * 16) ^ sw;
            short8 af[4], bfr[4];
            #pragma unroll
            for (int q = 0; q < 4; ++q) {
                af[q]  = *(const short8*)(ldsA + (wr * 64 + q * 16 + lrow) * 128 + kbl);
                bfr[q] = *(const short8*)(ldsB + (wc * 64 + q * 16 + lrow) * 128 + kbl);
            }
            #pragma unroll
            for (int mi = 0; mi < 4; ++mi)
                #pragma unroll
                for (int ni = 0; ni < 4; ++ni)
                    acc[mi][ni] = __builtin_amdgcn_mfma_f32_16x16x32_bf16(
                        af[mi], bfr[ni], acc[mi][ni], 0, 0, 0);
        }
    }

    // epilogue: ni innermost -> stores covering one line are consecutive
    const int cB = nBase + wc * 64 + lrow;
    const int rB = mBase + wr * 64 + lk * 4;
    float bs[4];
    #pragma unroll
    for (int ni = 0; ni < 4; ++ni) bs[ni] = bias[cB + ni * 16];
    #pragma unroll
    for (int mi = 0; mi < 4; ++mi) {
        #pragma unroll
        for (int i = 0; i < 4; ++i) {
            const int r = rB + mi * 16 + i;
            const int dst = (MODE == MODE_PROJ) ? src_row_idx(r) : r;
            #pragma unroll
            for (int ni = 0; ni < 4; ++ni) {
                const int c = cB + ni * 16;
                float v = acc[mi][ni][i] + bs[ni];
                if constexpr (MODE == MODE_QKV) {
                    float ve = __bfloat162float(vemb[(size_t)r * 256 + (c & 255)]);
                    v += (c >= 512) ? 2.f * ve : ve;   // v-path carries qkv2 + 2*vemb
                    ((bf16*)outp)[(size_t)r * 768 + c] = __float2bfloat16(v);
                } else if constexpr (MODE == MODE_PROJ) {
                    ((float*)outp)[(size_t)dst * 256 + c] =
                        resid[(size_t)dst * 256 + c] + v;
                } else if constexpr (MODE == MODE_FC1) {
                    float gl = 0.5f * v * (1.f + erff(v * 0.70710678118f));
                    ((bf16*)outp)[(size_t)r * 1024 + c] = __float2bfloat16(gl);
                } else {  // FC2: final residual add, f32 out
                    ((float*)outp)[(size_t)r * 256 + c] =
                        resid[(size_t)r * 256 + c] + v;
                }
            }
        }
    }
}

// ---------------- attention v3: head-parallel, zero inner barriers ---------
__global__ __launch_bounds__(256)
void attn_kernel(const bf16* __restrict__ qkv, const float* __restrict__ polar,
                 const float* __restrict__ rw1, const float* __restrict__ rb1,
                 const float* __restrict__ rw2, const float* __restrict__ rb2,
                 const float* __restrict__ tau, const float* __restrict__ mask,
                 bf16* __restrict__ outp) {
    const int w  = blockIdx.x;
    const int wl = w & 255;
    const int t  = threadIdx.x;
    const int lane = t & 63, wid = t >> 6;
    const int l15 = lane & 15, q4 = lane >> 4;
    const size_t wbase = (size_t)w * NWIN;
    const short* qs = (const short*)qkv;

    __shared__ float pwx[NWIN], pwy[NWIN];
    __shared__ float rqn[8][64], rkn[8][64];
    __shared__ float cw1s[32], cb1s[16], cw2s[8][16], rb2s[8], scts[8];
    __shared__ short rpem[8][2401];

    if (t < 98) {
        int n = t >> 1, cix = t & 1;
        int srow = src_row_idx(w * NWIN + n);
        float v = polar[(size_t)srow * 2 + cix];
        if (cix) pwy[n] = v; else pwx[n] = v;
    }
    if (t >= 128 && t < 256) {
        int u = t - 128;
        if (u < 128) cw2s[u >> 4][u & 15] = rw2[u];
    }
    if (t < 32) cw1s[t] = rw1[t];
    else if (t < 48) cb1s[t - 32] = rb1[t - 32];
    else if (t < 56) rb2s[t - 48] = rb2[t - 48];
    else if (t < 64) scts[t - 56] = SCALE / fmaxf(tau[t - 56], 0.01f);

    for (int idx = t; idx < 8 * NWIN; idx += 256) {
        int h = idx / NWIN, n = idx - h * NWIN;
        const bf16* qp = qkv + (wbase + n) * 768 + h * 32;
        float sq = 0, sk = 0;
        #pragma unroll
        for (int c = 0; c < 4; ++c) {
            short8 qv = *(const short8*)(qp + c * 8);
            short8 kv = *(const short8*)(qp + 256 + c * 8);
            #pragma unroll
            for (int j = 0; j < 8; ++j) {
                float qf = bf2f(qv[j]); sq += qf * qf;
                float kf = bf2f(kv[j]); sk += kf * kf;
            }
        }
        rqn[h][n] = rsqrtf(sq);
        rkn[h][n] = rsqrtf(sk);
    }
    __syncthreads();

    for (int e = t; e < NWIN * NWIN; e += 256) {
        int n = e / NWIN, m = e - n * NWIN;
        float dx = pwx[n] - pwx[m], dy = pwy[n] - pwy[m];
        float hid[16];
        #pragma unroll
        for (int o = 0; o < 16; ++o)
            hid[o] = fmaxf(fmaf(cw1s[2*o], dx, fmaf(cw1s[2*o+1], dy, cb1s[o])), 0.f);
        float mv = mask[(size_t)wl * NWIN * NWIN + e];
        #pragma unroll
        for (int h = 0; h < 8; ++h) {
            float a = rb2s[h] + mv;
            #pragma unroll
            for (int o = 0; o < 16; ++o) a = fmaf(hid[o], cw2s[h][o], a);
            rpem[h][e] = f2bfbits(a);
        }
    }
    __syncthreads();

    const short8 z8 = {0,0,0,0,0,0,0,0};
    const int qa  = (q4 & 1) * 2;
    const int sel = q4 >> 1;

    for (int hh = 0; hh < 2; ++hh) {
        const int h = wid + hh * 4;
        const bf16* hbase = qkv + wbase * 768 + h * 32;
        const float sct = scts[h];

        short8 kf[4], qf[4];
        #pragma unroll
        for (int at = 0; at < 4; ++at) {
            int m = at * 16 + l15;
            kf[at] = (m < NWIN) ? *(const short8*)(hbase + (size_t)m * 768 + 256 + q4 * 8) : z8;
        }
        #pragma unroll
        for (int nt = 0; nt < 4; ++nt) {
            int n = nt * 16 + l15;
            qf[nt] = (n < NWIN) ? *(const short8*)(hbase + (size_t)n * 768 + q4 * 8) : z8;
        }
        short8 vb[2][2];
        #pragma unroll
        for (int ks = 0; ks < 2; ++ks)
            #pragma unroll
            for (int ct = 0; ct < 2; ++ct) {
                short tmp[8];
                #pragma unroll
                for (int j = 0; j < 8; ++j) {
                    int m = ks * 32 + q4 * 8 + j;
                    tmp[j] = (m < NWIN)
                        ? qs[(wbase + m) * 768 + 512 + h * 32 + ct * 16 + l15]
                        : (short)0;
                }
                __builtin_memcpy(&vb[ks][ct], tmp, 16);
            }

        u32 pw[4][4][2];
        const f32x4 zf = {0.f, 0.f, 0.f, 0.f};
        #pragma unroll
        for (int nt = 0; nt < 4; ++nt) {
            f32x4 sacc[4];
            #pragma unroll
            for (int at = 0; at < 4; ++at)
                sacc[at] = __builtin_amdgcn_mfma_f32_16x16x32_bf16(kf[at], qf[nt], zf, 0, 0, 0);
            const int n = nt * 16 + l15;
            const float rq = rqn[h][n];
            float pv[4][4];
            #pragma unroll
            for (int at = 0; at < 4; ++at)
                #pragma unroll
                for (int i = 0; i < 4; ++i) {
                    int m = at * 16 + q4 * 4 + i;
                    float val = -1e30f;
                    if (n < NWIN && m < NWIN) {
                        float rr = fminf(rq * rkn[h][m], 1e6f);
                        val = sacc[at][i] * sct * rr + bf2f(rpem[h][n * NWIN + m]);
                    }
                    pv[at][i] = val;
                }
            float mx = -1e30f;
            #pragma unroll
            for (int at = 0; at < 4; ++at)
                #pragma unroll
                for (int i = 0; i < 4; ++i) mx = fmaxf(mx, pv[at][i]);
            mx = fmaxf(mx, __shfl_xor(mx, 16));
            mx = fmaxf(mx, __shfl_xor(mx, 32));
            float sum = 0.f;
            #pragma unroll
            for (int at = 0; at < 4; ++at)
                #pragma unroll
                for (int i = 0; i < 4; ++i) {
                    float ev = __expf(pv[at][i] - mx);
                    pv[at][i] = ev; sum += ev;
                }
            sum += __shfl_xor(sum, 16);
            sum += __shfl_xor(sum, 32);
            const float inv = 1.0f / sum;
            #pragma unroll
            for (int at = 0; at < 4; ++at) {
                pw[nt][at][0] = pack2bf(pv[at][0] * inv, pv[at][1] * inv);
                pw[nt][at][1] = pack2bf(pv[at][2] * inv, pv[at][3] * inv);
            }
        }

        f32x4 o[4][2] = {};
        #pragma unroll
        for (int nt = 0; nt < 4; ++nt) {
            #pragma unroll
            for (int ks = 0; ks < 2; ++ks) {
                u32 wv[4];
                #pragma unroll
                for (int w_ = 0; w_ < 4; ++w_) {
                    int srcl = l15 + (qa + (w_ >> 1)) * 16;
                    u32 lo = (u32)__shfl((int)pw[nt][2 * ks][w_ & 1], srcl);
                    u32 hi = (u32)__shfl((int)pw[nt][2 * ks + 1][w_ & 1], srcl);
                    wv[w_] = sel ? hi : lo;
                }
                short8 pa;
                __builtin_memcpy(&pa, wv, 16);
                #pragma unroll
                for (int ct = 0; ct < 2; ++ct)
                    o[nt][ct] = __builtin_amdgcn_mfma_f32_16x16x32_bf16(pa, vb[ks][ct], o[nt][ct], 0, 0, 0);
            }
        }

        #pragma unroll
        for (int nt = 0; nt < 4; ++nt)
            #pragma unroll
            for (int ct = 0; ct < 2; ++ct)
                #pragma unroll
                for (int i = 0; i < 4; ++i) {
                    int n = nt * 16 + q4 * 4 + i;
                    if (n < NWIN)
                        outp[(wbase + n) * 256 + h * 32 + ct * 16 + l15] =
                            __float2bfloat16(o[nt][ct][i]);
                }
    }
}

// ---------------- launch ----------------
extern "C" void kernel_launch(void* const* d_in, const int* in_sizes, int n_in,
                              void* d_out, int out_size, void* d_ws, size_t ws_size,
                              hipStream_t stream) {
    const float* x     = (const float*)d_in[0];
    const float* mask  = (const float*)d_in[1];
    const float* polar = (const float*)d_in[2];
    const float* vote  = (const float*)d_in[3];
    const float* g1    = (const float*)d_in[4];
    const float* be1   = (const float*)d_in[5];
    const float* wqkv  = (const float*)d_in[6];
    const float* bqkv  = (const float*)d_in[7];
    const float* wproj = (const float*)d_in[8];
    const float* bproj = (const float*)d_in[9];
    const float* tau   = (const float*)d_in[10];
    const float* rw1   = (const float*)d_in[11];
    const float* rb1   = (const float*)d_in[12];
    const float* rw2   = (const float*)d_in[13];
    const float* rb2   = (const float*)d_in[14];
    const float* vw1   = (const float*)d_in[15];
    const float* vb1   = (const float*)d_in[16];
    const float* vw2   = (const float*)d_in[17];
    const float* vb2   = (const float*)d_in[18];
    const float* g2    = (const float*)d_in[19];
    const float* be2   = (const float*)d_in[20];
    const float* fc1w  = (const float*)d_in[21];
    const float* fc1b  = (const float*)d_in[22];
    const float* fc2w  = (const float*)d_in[23];
    const float* fc2b  = (const float*)d_in[24];
    float* out = (float*)d_out;

    // workspace (bytes), max offset 130,826,240 (~124.8 MiB):
    //   qkv    [0, 77,070,336)            bf16 [M][768]  dead after attn
    //   R2     [77,070,336, 102,760,448)  vemb -> attnout (sequential lives)
    //   hbuf   [0, 102,760,448)           bf16 [M][1024] overlays qkv+R2
    //   weights[102,760,448, 104,333,312) bf16
    //   lnbuf  [105,136,128, 130,826,240) bf16 [M][256]: xw then x2n
    char* base = (char*)d_ws;
    bf16*  qkv     = (bf16*)base;
    bf16*  vemb    = (bf16*)(base + 77070336);
    bf16*  attnout = (bf16*)(base + 77070336);
    bf16*  hbuf    = (bf16*)base;
    bf16*  wqkvb   = (bf16*)(base + 102760448);
    bf16*  wprojb  = wqkvb + 768 * 256;
    bf16*  fc1wb   = wprojb + 256 * 256;
    bf16*  fc2wb   = fc1wb + 1024 * 256;
    bf16*  lnbuf   = (bf16*)(base + 105136128);

    cvt_w<<<192, 256, 0, stream>>>(wqkv, wqkvb, 768*256/4);
    cvt_w<<<64,  256, 0, stream>>>(wproj, wprojb, 256*256/4);
    cvt_w<<<256, 256, 0, stream>>>(fc1w, fc1wb, 1024*256/4);
    cvt_w<<<256, 256, 0, stream>>>(fc2w, fc2wb, 256*1024/4);

    prep_ln<<<M / 4, 256, 0, stream>>>(x, g1, be1, lnbuf, 1);       // xw
    vemb_kernel<<<M / 64, 256, 0, stream>>>(vote, vw1, vb1, vw2, vb2, vemb);

    mfma_gemm<MODE_QKV, 6><<<(M / 128) * 6, 256, 0, stream>>>(
        lnbuf, wqkvb, bqkv, vemb, nullptr, qkv);

    attn_kernel<<<BT, 256, 0, stream>>>(qkv, polar, rw1, rb1, rw2, rb2, tau, mask, attnout);

    mfma_gemm<MODE_PROJ, 2><<<(M / 128) * 2, 256, 0, stream>>>(
        attnout, wprojb, bproj, nullptr, x, out);

    prep_ln<<<M / 4, 256, 0, stream>>>(out, g2, be2, lnbuf, 0);     // x2n

    mfma_gemm<MODE_FC1, 8><<<(M / 128) * 8, 256, 0, stream>>>(
        lnbuf, fc1wb, fc1b, nullptr, nullptr, hbuf);

    mfma_gemm<MODE_FC2, 2><<<(M / 128) * 2, 256, 0, stream>>>(
        hbuf, fc2wb, fc2b, nullptr, out, out);
}

// Round 18
// 331.955 us; speedup vs baseline: 1.1087x; 1.1087x over previous
//
#include <hip/hip_runtime.h>
#include <hip/hip_bf16.h>
#include <math.h>

using bf16 = __hip_bfloat16;
typedef __attribute__((ext_vector_type(8))) short short8;
typedef __attribute__((ext_vector_type(4))) float f32x4;
typedef unsigned int u32;

// ---------------- problem constants ----------------
constexpr int BB    = 4;
constexpr int Hh    = 112;
constexpr int Ww    = 112;
constexpr int C     = 256;
constexpr int L     = Hh * Ww;        // 12544
constexpr int HEADS = 8;
constexpr int WS    = 7;
constexpr int SHIFT = 3;
constexpr int HID   = 1024;
constexpr int HD    = 32;
constexpr int NWIN  = 49;
constexpr int NW    = 256;
constexpr int BT    = BB * NW;        // 1024 windows
constexpr int M     = BT * NWIN;      // 50176 tokens
constexpr float SCALE = 0.17677669529663687f;
constexpr float EPS   = 1e-5f;

// window-token r -> natural token index. Same map for gather and scatter.
__device__ __forceinline__ int src_row_idx(int r) {
    int b_ = r / NWIN;
    int n  = r - b_ * NWIN;
    int b  = b_ >> 8;
    int w  = b_ & 255;
    int wh = w >> 4, ww = w & 15;
    int i  = n / WS, j = n - i * WS;
    int hp = wh * WS + i, wp = ww * WS + j;
    int h  = hp + SHIFT; if (h >= Hh) h -= Hh;
    int wc = wp + SHIFT; if (wc >= Ww) wc -= Ww;
    return b * L + h * Ww + wc;
}

__device__ __forceinline__ float bf2f(short s) {
    u32 u = ((u32)(unsigned short)s) << 16;
    float f; __builtin_memcpy(&f, &u, 4); return f;
}
__device__ __forceinline__ short f2bfbits(float f) {
    bf16 b = __float2bfloat16(f);
    short s; __builtin_memcpy(&s, &b, 2); return s;
}
__device__ __forceinline__ u32 pack2bf(float lo, float hi) {
    return (u32)(unsigned short)f2bfbits(lo) | ((u32)(unsigned short)f2bfbits(hi) << 16);
}

#define GL2LDS(g, l) __builtin_amdgcn_global_load_lds( \
    (const __attribute__((address_space(1))) u32*)(const void*)(g), \
    (__attribute__((address_space(3))) u32*)(void*)(l), 16, 0, 0)

// ---------------- fused LN (+optional gather) -> bf16 ----------------
__global__ __launch_bounds__(256)
void prep_ln(const float* __restrict__ x, const float* __restrict__ g,
             const float* __restrict__ b, bf16* __restrict__ o, int gather) {
    int wave = threadIdx.x >> 6, lane = threadIdx.x & 63;
    int tok = blockIdx.x * 4 + wave;
    int srow = gather ? src_row_idx(tok) : tok;
    float4 v = *(const float4*)&x[(size_t)srow * C + lane * 4];
    float s  = v.x + v.y + v.z + v.w;
    float s2 = v.x*v.x + v.y*v.y + v.z*v.z + v.w*v.w;
    #pragma unroll
    for (int ofs = 32; ofs > 0; ofs >>= 1) {
        s  += __shfl_xor(s, ofs);
        s2 += __shfl_xor(s2, ofs);
    }
    float m    = s * (1.f / C);
    float rstd = rsqrtf(s2 * (1.f / C) - m * m + EPS);
    float4 gv = *(const float4*)&g[lane * 4];
    float4 bv = *(const float4*)&b[lane * 4];
    uint2 u;
    u.x = pack2bf((v.x - m) * rstd * gv.x + bv.x, (v.y - m) * rstd * gv.y + bv.y);
    u.y = pack2bf((v.z - m) * rstd * gv.z + bv.z, (v.w - m) * rstd * gv.w + bv.w);
    *(uint2*)&o[(size_t)tok * C + lane * 4] = u;
}

// ---------------- f32 -> bf16 weight convert ----------------
__global__ __launch_bounds__(256)
void cvt_w(const float* __restrict__ in, bf16* __restrict__ o, int n4) {
    int i = blockIdx.x * 256 + threadIdx.x;
    if (i >= n4) return;
    float4 v = *(const float4*)&in[(size_t)i * 4];
    bf16 t4[4] = {__float2bfloat16(v.x), __float2bfloat16(v.y),
                  __float2bfloat16(v.z), __float2bfloat16(v.w)};
    *(uint2*)&o[(size_t)i * 4] = *(const uint2*)t4;
}

// ---------------- vote-embed MLP: wave-per-token, coalesced writes ----------
// Block = 64 tokens (4 waves x 16 iters). Lane l owns channels 4l..4l+3:
// w2 staged TRANSPOSED (w2t[o][c]) so lane reads float4 &w2t[o][l*4] --
// 64 contiguous 16B chunks = conflict-free b128. Writes: lane stores uint2
// at r*256+l*4 -> 512B contiguous per store inst (fixes the scattered-16B
// write pattern that capped R16/R17 at ~71us / 371 GB/s).
__global__ __launch_bounds__(256)
void vemb_kernel(const float* __restrict__ vote,
                 const float* __restrict__ w1, const float* __restrict__ b1,
                 const float* __restrict__ w2, const float* __restrict__ b2,
                 bf16* __restrict__ vemb) {
    __shared__ float w2t[16][256];     // transposed, 16 KB
    __shared__ float w1s[48], b1s[16];
    const int tid = threadIdx.x;
    {   // stage: thread t reads w2 row t (64B coalesced), scatters to w2t[o][t]
        const float4* src = (const float4*)(w2 + tid * 16);
        float4 r0 = src[0], r1 = src[1], r2 = src[2], r3 = src[3];
        float rr[16] = {r0.x, r0.y, r0.z, r0.w, r1.x, r1.y, r1.z, r1.w,
                        r2.x, r2.y, r2.z, r2.w, r3.x, r3.y, r3.z, r3.w};
        #pragma unroll
        for (int o = 0; o < 16; ++o) w2t[o][tid] = rr[o];   // stride-1: no conflict
        if (tid < 48) w1s[tid] = w1[tid];
        else if (tid < 64) b1s[tid - 48] = b1[tid - 48];
    }
    __syncthreads();

    const int wv = tid >> 6, l = tid & 63;
    const float4 bb = *(const float4*)&b2[l * 4];   // per-lane bias, coalesced

    for (int it = 0; it < 16; ++it) {
        const int r = blockIdx.x * 64 + wv * 16 + it;
        const int srow = src_row_idx(r);
        const float v0 = vote[(size_t)srow * 3];       // wave-uniform: broadcast
        const float v1 = vote[(size_t)srow * 3 + 1];
        const float v2 = vote[(size_t)srow * 3 + 2];
        float hid[16];
        #pragma unroll
        for (int o = 0; o < 16; ++o)
            hid[o] = fmaxf(fmaf(w1s[o*3], v0, fmaf(w1s[o*3+1], v1,
                           fmaf(w1s[o*3+2], v2, b1s[o]))), 0.f);
        float4 acc = bb;
        #pragma unroll
        for (int o = 0; o < 16; ++o) {
            float4 w = *(const float4*)&w2t[o][l * 4];  // b128 conflict-free
            acc.x = fmaf(hid[o], w.x, acc.x);
            acc.y = fmaf(hid[o], w.y, acc.y);
            acc.z = fmaf(hid[o], w.z, acc.z);
            acc.w = fmaf(hid[o], w.w, acc.w);
        }
        uint2 u;
        u.x = pack2bf(acc.x, acc.y);
        u.y = pack2bf(acc.z, acc.w);
        *(uint2*)&vemb[(size_t)r * 256 + l * 4] = u;    // coalesced 512B/wave
    }
}

// ---------------- MFMA GEMM: pure-DMA A+B, XCD-chunked swizzle ----------
enum { MODE_QKV = 0, MODE_PROJ = 1, MODE_FC1 = 2, MODE_FC2 = 3 };

template <int MODE, int NT>
__global__ __launch_bounds__(256)
void mfma_gemm(const bf16* __restrict__ A, const bf16* __restrict__ Wb,
               const float* __restrict__ bias,
               const bf16* __restrict__ vemb, const float* __restrict__ resid,
               void* __restrict__ outp) {
    constexpr int K = (MODE == MODE_FC2) ? 1024 : 256;
    __shared__ __align__(16) char lds[32768];
    char* ldsA = lds;
    char* ldsB = lds + 16384;

    const int tid  = threadIdx.x;
    const int lane = tid & 63;
    const int wid  = tid >> 6;
    const int wr   = wid >> 1, wc = wid & 1;
    const int lrow = lane & 15, lk = lane >> 4;

    const int cpx = gridDim.x >> 3;                   // nwg always %8==0
    const int lg  = (blockIdx.x & 7) * cpx + (blockIdx.x >> 3);
    const int bx  = lg / NT, by = lg % NT;
    const int mBase = bx * 128, nBase = by * 128;

    const int s_sub = tid >> 3;
    const int chunk = tid & 7;
    const int s_dst = (chunk * 16) ^ ((s_sub & 7) << 4);
    const char* bSrc = (const char*)(Wb + (size_t)(nBase + s_sub) * K) + s_dst;
    const char* aSrc = (const char*)(A  + (size_t)(mBase + s_sub) * K) + s_dst;

    f32x4 acc[4][4] = {};

    for (int t = 0; t < K / 64; ++t) {
        if (t) __syncthreads();
        #pragma unroll
        for (int r = 0; r < 4; ++r) {
            GL2LDS(bSrc + (size_t)r * 64 * K + (size_t)t * 128,
                   ldsB + r * 4096 + wid * 1024);
            GL2LDS(aSrc + (size_t)r * 64 * K + (size_t)t * 128,
                   ldsA + r * 4096 + wid * 1024);
        }
        __syncthreads();
        const int sw = (lrow & 7) << 4;
        #pragma unroll
        for (int ks = 0; ks < 2; ++ks) {
            const int kbl = (ks * 64 + lk * 16) ^ sw;
            short8 af[4], bfr[4];
            #pragma unroll
            for (int q = 0; q < 4; ++q) {
                af[q]  = *(const short8*)(ldsA + (wr * 64 + q * 16 + lrow) * 128 + kbl);
                bfr[q] = *(const short8*)(ldsB + (wc * 64 + q * 16 + lrow) * 128 + kbl);
            }
            #pragma unroll
            for (int mi = 0; mi < 4; ++mi)
                #pragma unroll
                for (int ni = 0; ni < 4; ++ni)
                    acc[mi][ni] = __builtin_amdgcn_mfma_f32_16x16x32_bf16(
                        af[mi], bfr[ni], acc[mi][ni], 0, 0, 0);
        }
    }

    // epilogue: ni innermost -> stores covering one line are consecutive
    const int cB = nBase + wc * 64 + lrow;
    const int rB = mBase + wr * 64 + lk * 4;
    float bs[4];
    #pragma unroll
    for (int ni = 0; ni < 4; ++ni) bs[ni] = bias[cB + ni * 16];
    #pragma unroll
    for (int mi = 0; mi < 4; ++mi) {
        #pragma unroll
        for (int i = 0; i < 4; ++i) {
            const int r = rB + mi * 16 + i;
            const int dst = (MODE == MODE_PROJ) ? src_row_idx(r) : r;
            #pragma unroll
            for (int ni = 0; ni < 4; ++ni) {
                const int c = cB + ni * 16;
                float v = acc[mi][ni][i] + bs[ni];
                if constexpr (MODE == MODE_QKV) {
                    float ve = __bfloat162float(vemb[(size_t)r * 256 + (c & 255)]);
                    v += (c >= 512) ? 2.f * ve : ve;   // v-path carries qkv2 + 2*vemb
                    ((bf16*)outp)[(size_t)r * 768 + c] = __float2bfloat16(v);
                } else if constexpr (MODE == MODE_PROJ) {
                    ((float*)outp)[(size_t)dst * 256 + c] =
                        resid[(size_t)dst * 256 + c] + v;
                } else if constexpr (MODE == MODE_FC1) {
                    float gl = 0.5f * v * (1.f + erff(v * 0.70710678118f));
                    ((bf16*)outp)[(size_t)r * 1024 + c] = __float2bfloat16(gl);
                } else {  // FC2: final residual add, f32 out
                    ((float*)outp)[(size_t)r * 256 + c] =
                        resid[(size_t)r * 256 + c] + v;
                }
            }
        }
    }
}

// ---------------- attention v3: head-parallel, zero inner barriers ---------
__global__ __launch_bounds__(256)
void attn_kernel(const bf16* __restrict__ qkv, const float* __restrict__ polar,
                 const float* __restrict__ rw1, const float* __restrict__ rb1,
                 const float* __restrict__ rw2, const float* __restrict__ rb2,
                 const float* __restrict__ tau, const float* __restrict__ mask,
                 bf16* __restrict__ outp) {
    const int w  = blockIdx.x;
    const int wl = w & 255;
    const int t  = threadIdx.x;
    const int lane = t & 63, wid = t >> 6;
    const int l15 = lane & 15, q4 = lane >> 4;
    const size_t wbase = (size_t)w * NWIN;
    const short* qs = (const short*)qkv;

    __shared__ float pwx[NWIN], pwy[NWIN];
    __shared__ float rqn[8][64], rkn[8][64];
    __shared__ float cw1s[32], cb1s[16], cw2s[8][16], rb2s[8], scts[8];
    __shared__ short rpem[8][2401];

    if (t < 98) {
        int n = t >> 1, cix = t & 1;
        int srow = src_row_idx(w * NWIN + n);
        float v = polar[(size_t)srow * 2 + cix];
        if (cix) pwy[n] = v; else pwx[n] = v;
    }
    if (t >= 128 && t < 256) {
        int u = t - 128;
        if (u < 128) cw2s[u >> 4][u & 15] = rw2[u];
    }
    if (t < 32) cw1s[t] = rw1[t];
    else if (t < 48) cb1s[t - 32] = rb1[t - 32];
    else if (t < 56) rb2s[t - 48] = rb2[t - 48];
    else if (t < 64) scts[t - 56] = SCALE / fmaxf(tau[t - 56], 0.01f);

    for (int idx = t; idx < 8 * NWIN; idx += 256) {
        int h = idx / NWIN, n = idx - h * NWIN;
        const bf16* qp = qkv + (wbase + n) * 768 + h * 32;
        float sq = 0, sk = 0;
        #pragma unroll
        for (int c = 0; c < 4; ++c) {
            short8 qv = *(const short8*)(qp + c * 8);
            short8 kv = *(const short8*)(qp + 256 + c * 8);
            #pragma unroll
            for (int j = 0; j < 8; ++j) {
                float qf = bf2f(qv[j]); sq += qf * qf;
                float kf = bf2f(kv[j]); sk += kf * kf;
            }
        }
        rqn[h][n] = rsqrtf(sq);
        rkn[h][n] = rsqrtf(sk);
    }
    __syncthreads();

    for (int e = t; e < NWIN * NWIN; e += 256) {
        int n = e / NWIN, m = e - n * NWIN;
        float dx = pwx[n] - pwx[m], dy = pwy[n] - pwy[m];
        float hid[16];
        #pragma unroll
        for (int o = 0; o < 16; ++o)
            hid[o] = fmaxf(fmaf(cw1s[2*o], dx, fmaf(cw1s[2*o+1], dy, cb1s[o])), 0.f);
        float mv = mask[(size_t)wl * NWIN * NWIN + e];
        #pragma unroll
        for (int h = 0; h < 8; ++h) {
            float a = rb2s[h] + mv;
            #pragma unroll
            for (int o = 0; o < 16; ++o) a = fmaf(hid[o], cw2s[h][o], a);
            rpem[h][e] = f2bfbits(a);
        }
    }
    __syncthreads();

    const short8 z8 = {0,0,0,0,0,0,0,0};
    const int qa  = (q4 & 1) * 2;
    const int sel = q4 >> 1;

    for (int hh = 0; hh < 2; ++hh) {
        const int h = wid + hh * 4;
        const bf16* hbase = qkv + wbase * 768 + h * 32;
        const float sct = scts[h];

        short8 kf[4], qf[4];
        #pragma unroll
        for (int at = 0; at < 4; ++at) {
            int m = at * 16 + l15;
            kf[at] = (m < NWIN) ? *(const short8*)(hbase + (size_t)m * 768 + 256 + q4 * 8) : z8;
        }
        #pragma unroll
        for (int nt = 0; nt < 4; ++nt) {
            int n = nt * 16 + l15;
            qf[nt] = (n < NWIN) ? *(const short8*)(hbase + (size_t)n * 768 + q4 * 8) : z8;
        }
        short8 vb[2][2];
        #pragma unroll
        for (int ks = 0; ks < 2; ++ks)
            #pragma unroll
            for (int ct = 0; ct < 2; ++ct) {
                short tmp[8];
                #pragma unroll
                for (int j = 0; j < 8; ++j) {
                    int m = ks * 32 + q4 * 8 + j;
                    tmp[j] = (m < NWIN)
                        ? qs[(wbase + m) * 768 + 512 + h * 32 + ct * 16 + l15]
                        : (short)0;
                }
                __builtin_memcpy(&vb[ks][ct], tmp, 16);
            }

        u32 pw[4][4][2];
        const f32x4 zf = {0.f, 0.f, 0.f, 0.f};
        #pragma unroll
        for (int nt = 0; nt < 4; ++nt) {
            f32x4 sacc[4];
            #pragma unroll
            for (int at = 0; at < 4; ++at)
                sacc[at] = __builtin_amdgcn_mfma_f32_16x16x32_bf16(kf[at], qf[nt], zf, 0, 0, 0);
            const int n = nt * 16 + l15;
            const float rq = rqn[h][n];
            float pv[4][4];
            #pragma unroll
            for (int at = 0; at < 4; ++at)
                #pragma unroll
                for (int i = 0; i < 4; ++i) {
                    int m = at * 16 + q4 * 4 + i;
                    float val = -1e30f;
                    if (n < NWIN && m < NWIN) {
                        float rr = fminf(rq * rkn[h][m], 1e6f);
                        val = sacc[at][i] * sct * rr + bf2f(rpem[h][n * NWIN + m]);
                    }
                    pv[at][i] = val;
                }
            float mx = -1e30f;
            #pragma unroll
            for (int at = 0; at < 4; ++at)
                #pragma unroll
                for (int i = 0; i < 4; ++i) mx = fmaxf(mx, pv[at][i]);
            mx = fmaxf(mx, __shfl_xor(mx, 16));
            mx = fmaxf(mx, __shfl_xor(mx, 32));
            float sum = 0.f;
            #pragma unroll
            for (int at = 0; at < 4; ++at)
                #pragma unroll
                for (int i = 0; i < 4; ++i) {
                    float ev = __expf(pv[at][i] - mx);
                    pv[at][i] = ev; sum += ev;
                }
            sum += __shfl_xor(sum, 16);
            sum += __shfl_xor(sum, 32);
            const float inv = 1.0f / sum;
            #pragma unroll
            for (int at = 0; at < 4; ++at) {
                pw[nt][at][0] = pack2bf(pv[at][0] * inv, pv[at][1] * inv);
                pw[nt][at][1] = pack2bf(pv[at][2] * inv, pv[at][3] * inv);
            }
        }

        f32x4 o[4][2] = {};
        #pragma unroll
        for (int nt = 0; nt < 4; ++nt) {
            #pragma unroll
            for (int ks = 0; ks < 2; ++ks) {
                u32 wv[4];
                #pragma unroll
                for (int w_ = 0; w_ < 4; ++w_) {
                    int srcl = l15 + (qa + (w_ >> 1)) * 16;
                    u32 lo = (u32)__shfl((int)pw[nt][2 * ks][w_ & 1], srcl);
                    u32 hi = (u32)__shfl((int)pw[nt][2 * ks + 1][w_ & 1], srcl);
                    wv[w_] = sel ? hi : lo;
                }
                short8 pa;
                __builtin_memcpy(&pa, wv, 16);
                #pragma unroll
                for (int ct = 0; ct < 2; ++ct)
                    o[nt][ct] = __builtin_amdgcn_mfma_f32_16x16x32_bf16(pa, vb[ks][ct], o[nt][ct], 0, 0, 0);
            }
        }

        #pragma unroll
        for (int nt = 0; nt < 4; ++nt)
            #pragma unroll
            for (int ct = 0; ct < 2; ++ct)
                #pragma unroll
                for (int i = 0; i < 4; ++i) {
                    int n = nt * 16 + q4 * 4 + i;
                    if (n < NWIN)
                        outp[(wbase + n) * 256 + h * 32 + ct * 16 + l15] =
                            __float2bfloat16(o[nt][ct][i]);
                }
    }
}

// ---------------- launch ----------------
extern "C" void kernel_launch(void* const* d_in, const int* in_sizes, int n_in,
                              void* d_out, int out_size, void* d_ws, size_t ws_size,
                              hipStream_t stream) {
    const float* x     = (const float*)d_in[0];
    const float* mask  = (const float*)d_in[1];
    const float* polar = (const float*)d_in[2];
    const float* vote  = (const float*)d_in[3];
    const float* g1    = (const float*)d_in[4];
    const float* be1   = (const float*)d_in[5];
    const float* wqkv  = (const float*)d_in[6];
    const float* bqkv  = (const float*)d_in[7];
    const float* wproj = (const float*)d_in[8];
    const float* bproj = (const float*)d_in[9];
    const float* tau   = (const float*)d_in[10];
    const float* rw1   = (const float*)d_in[11];
    const float* rb1   = (const float*)d_in[12];
    const float* rw2   = (const float*)d_in[13];
    const float* rb2   = (const float*)d_in[14];
    const float* vw1   = (const float*)d_in[15];
    const float* vb1   = (const float*)d_in[16];
    const float* vw2   = (const float*)d_in[17];
    const float* vb2   = (const float*)d_in[18];
    const float* g2    = (const float*)d_in[19];
    const float* be2   = (const float*)d_in[20];
    const float* fc1w  = (const float*)d_in[21];
    const float* fc1b  = (const float*)d_in[22];
    const float* fc2w  = (const float*)d_in[23];
    const float* fc2b  = (const float*)d_in[24];
    float* out = (float*)d_out;

    // workspace (bytes), max offset 130,826,240 (~124.8 MiB):
    //   qkv    [0, 77,070,336)            bf16 [M][768]  dead after attn
    //   R2     [77,070,336, 102,760,448)  vemb -> attnout (sequential lives)
    //   hbuf   [0, 102,760,448)           bf16 [M][1024] overlays qkv+R2
    //   weights[102,760,448, 104,333,312) bf16
    //   lnbuf  [105,136,128, 130,826,240) bf16 [M][256]: xw then x2n
    char* base = (char*)d_ws;
    bf16*  qkv     = (bf16*)base;
    bf16*  vemb    = (bf16*)(base + 77070336);
    bf16*  attnout = (bf16*)(base + 77070336);
    bf16*  hbuf    = (bf16*)base;
    bf16*  wqkvb   = (bf16*)(base + 102760448);
    bf16*  wprojb  = wqkvb + 768 * 256;
    bf16*  fc1wb   = wprojb + 256 * 256;
    bf16*  fc2wb   = fc1wb + 1024 * 256;
    bf16*  lnbuf   = (bf16*)(base + 105136128);

    cvt_w<<<192, 256, 0, stream>>>(wqkv, wqkvb, 768*256/4);
    cvt_w<<<64,  256, 0, stream>>>(wproj, wprojb, 256*256/4);
    cvt_w<<<256, 256, 0, stream>>>(fc1w, fc1wb, 1024*256/4);
    cvt_w<<<256, 256, 0, stream>>>(fc2w, fc2wb, 256*1024/4);

    prep_ln<<<M / 4, 256, 0, stream>>>(x, g1, be1, lnbuf, 1);       // xw
    vemb_kernel<<<M / 64, 256, 0, stream>>>(vote, vw1, vb1, vw2, vb2, vemb);

    mfma_gemm<MODE_QKV, 6><<<(M / 128) * 6, 256, 0, stream>>>(
        lnbuf, wqkvb, bqkv, vemb, nullptr, qkv);

    attn_kernel<<<BT, 256, 0, stream>>>(qkv, polar, rw1, rb1, rw2, rb2, tau, mask, attnout);

    mfma_gemm<MODE_PROJ, 2><<<(M / 128) * 2, 256, 0, stream>>>(
        attnout, wprojb, bproj, nullptr, x, out);

    prep_ln<<<M / 4, 256, 0, stream>>>(out, g2, be2, lnbuf, 0);     // x2n

    mfma_gemm<MODE_FC1, 8><<<(M / 128) * 8, 256, 0, stream>>>(
        lnbuf, fc1wb, fc1b, nullptr, nullptr, hbuf);

    mfma_gemm<MODE_FC2, 2><<<(M / 128) * 2, 256, 0, stream>>>(
        hbuf, fc2wb, fc2b, nullptr, out, out);
}

// Round 21
// 304.618 us; speedup vs baseline: 1.2082x; 1.0897x over previous
//
#include <hip/hip_runtime.h>
#include <hip/hip_bf16.h>
#include <math.h>

using bf16 = __hip_bfloat16;
typedef __attribute__((ext_vector_type(8))) short short8;
typedef __attribute__((ext_vector_type(4))) float f32x4;
typedef unsigned int u32;

// ---------------- problem constants ----------------
constexpr int BB    = 4;
constexpr int Hh    = 112;
constexpr int Ww    = 112;
constexpr int C     = 256;
constexpr int L     = Hh * Ww;        // 12544
constexpr int HEADS = 8;
constexpr int WS    = 7;
constexpr int SHIFT = 3;
constexpr int HID   = 1024;
constexpr int HD    = 32;
constexpr int NWIN  = 49;
constexpr int NW    = 256;
constexpr int BT    = BB * NW;        // 1024 windows
constexpr int M     = BT * NWIN;      // 50176 tokens
constexpr float SCALE = 0.17677669529663687f;
constexpr float EPS   = 1e-5f;

// window-token r -> natural token index. Same map for gather and scatter.
__device__ __forceinline__ int src_row_idx(int r) {
    int b_ = r / NWIN;
    int n  = r - b_ * NWIN;
    int b  = b_ >> 8;
    int w  = b_ & 255;
    int wh = w >> 4, ww = w & 15;
    int i  = n / WS, j = n - i * WS;
    int hp = wh * WS + i, wp = ww * WS + j;
    int h  = hp + SHIFT; if (h >= Hh) h -= Hh;
    int wc = wp + SHIFT; if (wc >= Ww) wc -= Ww;
    return b * L + h * Ww + wc;
}

__device__ __forceinline__ float bf2f(short s) {
    u32 u = ((u32)(unsigned short)s) << 16;
    float f; __builtin_memcpy(&f, &u, 4); return f;
}
__device__ __forceinline__ short f2bfbits(float f) {
    bf16 b = __float2bfloat16(f);
    short s; __builtin_memcpy(&s, &b, 2); return s;
}
__device__ __forceinline__ u32 pack2bf(float lo, float hi) {
    return (u32)(unsigned short)f2bfbits(lo) | ((u32)(unsigned short)f2bfbits(hi) << 16);
}

#define GL2LDS(g, l) __builtin_amdgcn_global_load_lds( \
    (const __attribute__((address_space(1))) u32*)(const void*)(g), \
    (__attribute__((address_space(3))) u32*)(void*)(l), 16, 0, 0)

// ---------------- fused LN (+optional gather) -> bf16 ----------------
__global__ __launch_bounds__(256)
void prep_ln(const float* __restrict__ x, const float* __restrict__ g,
             const float* __restrict__ b, bf16* __restrict__ o, int gather) {
    int wave = threadIdx.x >> 6, lane = threadIdx.x & 63;
    int tok = blockIdx.x * 4 + wave;
    int srow = gather ? src_row_idx(tok) : tok;
    float4 v = *(const float4*)&x[(size_t)srow * C + lane * 4];
    float s  = v.x + v.y + v.z + v.w;
    float s2 = v.x*v.x + v.y*v.y + v.z*v.z + v.w*v.w;
    #pragma unroll
    for (int ofs = 32; ofs > 0; ofs >>= 1) {
        s  += __shfl_xor(s, ofs);
        s2 += __shfl_xor(s2, ofs);
    }
    float m    = s * (1.f / C);
    float rstd = rsqrtf(s2 * (1.f / C) - m * m + EPS);
    float4 gv = *(const float4*)&g[lane * 4];
    float4 bv = *(const float4*)&b[lane * 4];
    uint2 u;
    u.x = pack2bf((v.x - m) * rstd * gv.x + bv.x, (v.y - m) * rstd * gv.y + bv.y);
    u.y = pack2bf((v.z - m) * rstd * gv.z + bv.z, (v.w - m) * rstd * gv.w + bv.w);
    *(uint2*)&o[(size_t)tok * C + lane * 4] = u;
}

// ---------------- f32 -> bf16 weight convert ----------------
__global__ __launch_bounds__(256)
void cvt_w(const float* __restrict__ in, bf16* __restrict__ o, int n4) {
    int i = blockIdx.x * 256 + threadIdx.x;
    if (i >= n4) return;
    float4 v = *(const float4*)&in[(size_t)i * 4];
    bf16 t4[4] = {__float2bfloat16(v.x), __float2bfloat16(v.y),
                  __float2bfloat16(v.z), __float2bfloat16(v.w)};
    *(uint2*)&o[(size_t)i * 4] = *(const uint2*)t4;
}

// ---------------- vote-embed MLP: wave-per-token, coalesced writes ----------
__global__ __launch_bounds__(256)
void vemb_kernel(const float* __restrict__ vote,
                 const float* __restrict__ w1, const float* __restrict__ b1,
                 const float* __restrict__ w2, const float* __restrict__ b2,
                 bf16* __restrict__ vemb) {
    __shared__ float w2t[16][256];     // transposed, 16 KB
    __shared__ float w1s[48], b1s[16];
    const int tid = threadIdx.x;
    {
        const float4* src = (const float4*)(w2 + tid * 16);
        float4 r0 = src[0], r1 = src[1], r2 = src[2], r3 = src[3];
        float rr[16] = {r0.x, r0.y, r0.z, r0.w, r1.x, r1.y, r1.z, r1.w,
                        r2.x, r2.y, r2.z, r2.w, r3.x, r3.y, r3.z, r3.w};
        #pragma unroll
        for (int o = 0; o < 16; ++o) w2t[o][tid] = rr[o];
        if (tid < 48) w1s[tid] = w1[tid];
        else if (tid < 64) b1s[tid - 48] = b1[tid - 48];
    }
    __syncthreads();

    const int wv = tid >> 6, l = tid & 63;
    const float4 bb = *(const float4*)&b2[l * 4];

    for (int it = 0; it < 16; ++it) {
        const int r = blockIdx.x * 64 + wv * 16 + it;
        const int srow = src_row_idx(r);
        const float v0 = vote[(size_t)srow * 3];
        const float v1 = vote[(size_t)srow * 3 + 1];
        const float v2 = vote[(size_t)srow * 3 + 2];
        float hid[16];
        #pragma unroll
        for (int o = 0; o < 16; ++o)
            hid[o] = fmaxf(fmaf(w1s[o*3], v0, fmaf(w1s[o*3+1], v1,
                           fmaf(w1s[o*3+2], v2, b1s[o]))), 0.f);
        float4 acc = bb;
        #pragma unroll
        for (int o = 0; o < 16; ++o) {
            float4 w = *(const float4*)&w2t[o][l * 4];
            acc.x = fmaf(hid[o], w.x, acc.x);
            acc.y = fmaf(hid[o], w.y, acc.y);
            acc.z = fmaf(hid[o], w.z, acc.z);
            acc.w = fmaf(hid[o], w.w, acc.w);
        }
        uint2 u;
        u.x = pack2bf(acc.x, acc.y);
        u.y = pack2bf(acc.z, acc.w);
        *(uint2*)&vemb[(size_t)r * 256 + l * 4] = u;
    }
}

// ---------------- MFMA GEMM: 256x128 tile, 8 waves, pure-DMA, XCD swizzle --
// BM=256, BN=128, BK=64. 512 thr = 8 waves (4x2 of 64x64). LDS: A 32KB +
// B 16KB = 48KB, [rows][64 bf16] byte^=((row&7)<<4) swizzled. Each r-chunk
// stages 64 rows (8 waves x 8 rows) -> global stride r*64 rows = r*128*K
// BYTES (the R19 bug was r*64*K bytes = 32 rows).
enum { MODE_QKV = 0, MODE_PROJ = 1, MODE_FC1 = 2, MODE_FC2 = 3 };

template <int MODE, int NT>
__global__ __launch_bounds__(512)
void mfma_gemm(const bf16* __restrict__ A, const bf16* __restrict__ Wb,
               const float* __restrict__ bias,
               const bf16* __restrict__ vemb, const float* __restrict__ resid,
               void* __restrict__ outp) {
    constexpr int K = (MODE == MODE_FC2) ? 1024 : 256;
    __shared__ __align__(16) char ldsA[32768];
    __shared__ __align__(16) char ldsB[16384];

    const int tid  = threadIdx.x;
    const int lane = tid & 63;
    const int wid  = tid >> 6;                // 0..7
    const int wr   = wid >> 1, wc = wid & 1;  // 4x2 wave grid
    const int lrow = lane & 15, lk = lane >> 4;

    const int cpx = gridDim.x >> 3;                   // nwg always %8==0
    const int lg  = (blockIdx.x & 7) * cpx + (blockIdx.x >> 3);
    const int bx  = lg / NT, by = lg % NT;
    const int mBase = bx * 256, nBase = by * 128;

    // staging: one wave per GL2LDS call writes 8 rows (1024B). lane -> row
    // lane>>3 within chunk, 16B piece lane&7, swizzle ((lane>>3)&7)<<4.
    const int sbyte = ((lane & 7) * 16) ^ ((lane >> 3) << 4);
    const char* aSrc = (const char*)(A  + (size_t)(mBase + wid * 8 + (lane >> 3)) * K) + sbyte;
    const char* bSrc = (const char*)(Wb + (size_t)(nBase + wid * 8 + (lane >> 3)) * K) + sbyte;

    f32x4 acc[4][4] = {};

    for (int t = 0; t < K / 64; ++t) {
        if (t) __syncthreads();
        const size_t kof = (size_t)t * 128;
        #pragma unroll
        for (int r = 0; r < 4; ++r)            // A: 4 chunks x 64 rows = 256
            GL2LDS(aSrc + (size_t)r * 128 * K + kof,
                   ldsA + (r * 8 + wid) * 1024);
        #pragma unroll
        for (int r = 0; r < 2; ++r)            // B: 2 chunks x 64 rows = 128
            GL2LDS(bSrc + (size_t)r * 128 * K + kof,
                   ldsB + (r * 8 + wid) * 1024);
        __syncthreads();
        const int sw = (lrow & 7) << 4;
        #pragma unroll
        for (int ks = 0; ks < 2; ++ks) {
            const int kbl = (ks * 64 + lk * 16) ^ sw;
            short8 af[4], bfr[4];
            #pragma unroll
            for (int q = 0; q < 4; ++q) {
                af[q]  = *(const short8*)(ldsA + (wr * 64 + q * 16 + lrow) * 128 + kbl);
                bfr[q] = *(const short8*)(ldsB + (wc * 64 + q * 16 + lrow) * 128 + kbl);
            }
            #pragma unroll
            for (int mi = 0; mi < 4; ++mi)
                #pragma unroll
                for (int ni = 0; ni < 4; ++ni)
                    acc[mi][ni] = __builtin_amdgcn_mfma_f32_16x16x32_bf16(
                        af[mi], bfr[ni], acc[mi][ni], 0, 0, 0);
        }
    }

    // epilogue: ni innermost -> stores covering one line are consecutive
    const int cB = nBase + wc * 64 + lrow;
    const int rB = mBase + wr * 64 + lk * 4;
    float bs[4];
    #pragma unroll
    for (int ni = 0; ni < 4; ++ni) bs[ni] = bias[cB + ni * 16];
    #pragma unroll
    for (int mi = 0; mi < 4; ++mi) {
        #pragma unroll
        for (int i = 0; i < 4; ++i) {
            const int r = rB + mi * 16 + i;
            const int dst = (MODE == MODE_PROJ) ? src_row_idx(r) : r;
            #pragma unroll
            for (int ni = 0; ni < 4; ++ni) {
                const int c = cB + ni * 16;
                float v = acc[mi][ni][i] + bs[ni];
                if constexpr (MODE == MODE_QKV) {
                    float ve = __bfloat162float(vemb[(size_t)r * 256 + (c & 255)]);
                    v += (c >= 512) ? 2.f * ve : ve;   // v-path carries qkv2 + 2*vemb
                    ((bf16*)outp)[(size_t)r * 768 + c] = __float2bfloat16(v);
                } else if constexpr (MODE == MODE_PROJ) {
                    ((float*)outp)[(size_t)dst * 256 + c] =
                        resid[(size_t)dst * 256 + c] + v;
                } else if constexpr (MODE == MODE_FC1) {
                    float gl = 0.5f * v * (1.f + erff(v * 0.70710678118f));
                    ((bf16*)outp)[(size_t)r * 1024 + c] = __float2bfloat16(gl);
                } else {  // FC2: final residual add, f32 out
                    ((float*)outp)[(size_t)r * 256 + c] =
                        resid[(size_t)r * 256 + c] + v;
                }
            }
        }
    }
}

// ---------------- attention v3: head-parallel, zero inner barriers ---------
__global__ __launch_bounds__(256)
void attn_kernel(const bf16* __restrict__ qkv, const float* __restrict__ polar,
                 const float* __restrict__ rw1, const float* __restrict__ rb1,
                 const float* __restrict__ rw2, const float* __restrict__ rb2,
                 const float* __restrict__ tau, const float* __restrict__ mask,
                 bf16* __restrict__ outp) {
    const int w  = blockIdx.x;
    const int wl = w & 255;
    const int t  = threadIdx.x;
    const int lane = t & 63, wid = t >> 6;
    const int l15 = lane & 15, q4 = lane >> 4;
    const size_t wbase = (size_t)w * NWIN;
    const short* qs = (const short*)qkv;

    __shared__ float pwx[NWIN], pwy[NWIN];
    __shared__ float rqn[8][64], rkn[8][64];
    __shared__ float cw1s[32], cb1s[16], cw2s[8][16], rb2s[8], scts[8];
    __shared__ short rpem[8][2401];

    if (t < 98) {
        int n = t >> 1, cix = t & 1;
        int srow = src_row_idx(w * NWIN + n);
        float v = polar[(size_t)srow * 2 + cix];
        if (cix) pwy[n] = v; else pwx[n] = v;
    }
    if (t >= 128 && t < 256) {
        int u = t - 128;
        if (u < 128) cw2s[u >> 4][u & 15] = rw2[u];
    }
    if (t < 32) cw1s[t] = rw1[t];
    else if (t < 48) cb1s[t - 32] = rb1[t - 32];
    else if (t < 56) rb2s[t - 48] = rb2[t - 48];
    else if (t < 64) scts[t - 56] = SCALE / fmaxf(tau[t - 56], 0.01f);

    for (int idx = t; idx < 8 * NWIN; idx += 256) {
        int h = idx / NWIN, n = idx - h * NWIN;
        const bf16* qp = qkv + (wbase + n) * 768 + h * 32;
        float sq = 0, sk = 0;
        #pragma unroll
        for (int c = 0; c < 4; ++c) {
            short8 qv = *(const short8*)(qp + c * 8);
            short8 kv = *(const short8*)(qp + 256 + c * 8);
            #pragma unroll
            for (int j = 0; j < 8; ++j) {
                float qf = bf2f(qv[j]); sq += qf * qf;
                float kf = bf2f(kv[j]); sk += kf * kf;
            }
        }
        rqn[h][n] = rsqrtf(sq);
        rkn[h][n] = rsqrtf(sk);
    }
    __syncthreads();

    for (int e = t; e < NWIN * NWIN; e += 256) {
        int n = e / NWIN, m = e - n * NWIN;
        float dx = pwx[n] - pwx[m], dy = pwy[n] - pwy[m];
        float hid[16];
        #pragma unroll
        for (int o = 0; o < 16; ++o)
            hid[o] = fmaxf(fmaf(cw1s[2*o], dx, fmaf(cw1s[2*o+1], dy, cb1s[o])), 0.f);
        float mv = mask[(size_t)wl * NWIN * NWIN + e];
        #pragma unroll
        for (int h = 0; h < 8; ++h) {
            float a = rb2s[h] + mv;
            #pragma unroll
            for (int o = 0; o < 16; ++o) a = fmaf(hid[o], cw2s[h][o], a);
            rpem[h][e] = f2bfbits(a);
        }
    }
    __syncthreads();

    const short8 z8 = {0,0,0,0,0,0,0,0};
    const int qa  = (q4 & 1) * 2;
    const int sel = q4 >> 1;

    for (int hh = 0; hh < 2; ++hh) {
        const int h = wid + hh * 4;
        const bf16* hbase = qkv + wbase * 768 + h * 32;
        const float sct = scts[h];

        short8 kf[4], qf[4];
        #pragma unroll
        for (int at = 0; at < 4; ++at) {
            int m = at * 16 + l15;
            kf[at] = (m < NWIN) ? *(const short8*)(hbase + (size_t)m * 768 + 256 + q4 * 8) : z8;
        }
        #pragma unroll
        for (int nt = 0; nt < 4; ++nt) {
            int n = nt * 16 + l15;
            qf[nt] = (n < NWIN) ? *(const short8*)(hbase + (size_t)n * 768 + q4 * 8) : z8;
        }
        short8 vb[2][2];
        #pragma unroll
        for (int ks = 0; ks < 2; ++ks)
            #pragma unroll
            for (int ct = 0; ct < 2; ++ct) {
                short tmp[8];
                #pragma unroll
                for (int j = 0; j < 8; ++j) {
                    int m = ks * 32 + q4 * 8 + j;
                    tmp[j] = (m < NWIN)
                        ? qs[(wbase + m) * 768 + 512 + h * 32 + ct * 16 + l15]
                        : (short)0;
                }
                __builtin_memcpy(&vb[ks][ct], tmp, 16);
            }

        u32 pw[4][4][2];
        const f32x4 zf = {0.f, 0.f, 0.f, 0.f};
        #pragma unroll
        for (int nt = 0; nt < 4; ++nt) {
            f32x4 sacc[4];
            #pragma unroll
            for (int at = 0; at < 4; ++at)
                sacc[at] = __builtin_amdgcn_mfma_f32_16x16x32_bf16(kf[at], qf[nt], zf, 0, 0, 0);
            const int n = nt * 16 + l15;
            const float rq = rqn[h][n];
            float pv[4][4];
            #pragma unroll
            for (int at = 0; at < 4; ++at)
                #pragma unroll
                for (int i = 0; i < 4; ++i) {
                    int m = at * 16 + q4 * 4 + i;
                    float val = -1e30f;
                    if (n < NWIN && m < NWIN) {
                        float rr = fminf(rq * rkn[h][m], 1e6f);
                        val = sacc[at][i] * sct * rr + bf2f(rpem[h][n * NWIN + m]);
                    }
                    pv[at][i] = val;
                }
            float mx = -1e30f;
            #pragma unroll
            for (int at = 0; at < 4; ++at)
                #pragma unroll
                for (int i = 0; i < 4; ++i) mx = fmaxf(mx, pv[at][i]);
            mx = fmaxf(mx, __shfl_xor(mx, 16));
            mx = fmaxf(mx, __shfl_xor(mx, 32));
            float sum = 0.f;
            #pragma unroll
            for (int at = 0; at < 4; ++at)
                #pragma unroll
                for (int i = 0; i < 4; ++i) {
                    float ev = __expf(pv[at][i] - mx);
                    pv[at][i] = ev; sum += ev;
                }
            sum += __shfl_xor(sum, 16);
            sum += __shfl_xor(sum, 32);
            const float inv = 1.0f / sum;
            #pragma unroll
            for (int at = 0; at < 4; ++at) {
                pw[nt][at][0] = pack2bf(pv[at][0] * inv, pv[at][1] * inv);
                pw[nt][at][1] = pack2bf(pv[at][2] * inv, pv[at][3] * inv);
            }
        }

        f32x4 o[4][2] = {};
        #pragma unroll
        for (int nt = 0; nt < 4; ++nt) {
            #pragma unroll
            for (int ks = 0; ks < 2; ++ks) {
                u32 wv[4];
                #pragma unroll
                for (int w_ = 0; w_ < 4; ++w_) {
                    int srcl = l15 + (qa + (w_ >> 1)) * 16;
                    u32 lo = (u32)__shfl((int)pw[nt][2 * ks][w_ & 1], srcl);
                    u32 hi = (u32)__shfl((int)pw[nt][2 * ks + 1][w_ & 1], srcl);
                    wv[w_] = sel ? hi : lo;
                }
                short8 pa;
                __builtin_memcpy(&pa, wv, 16);
                #pragma unroll
                for (int ct = 0; ct < 2; ++ct)
                    o[nt][ct] = __builtin_amdgcn_mfma_f32_16x16x32_bf16(pa, vb[ks][ct], o[nt][ct], 0, 0, 0);
            }
        }

        #pragma unroll
        for (int nt = 0; nt < 4; ++nt)
            #pragma unroll
            for (int ct = 0; ct < 2; ++ct)
                #pragma unroll
                for (int i = 0; i < 4; ++i) {
                    int n = nt * 16 + q4 * 4 + i;
                    if (n < NWIN)
                        outp[(wbase + n) * 256 + h * 32 + ct * 16 + l15] =
                            __float2bfloat16(o[nt][ct][i]);
                }
    }
}

// ---------------- launch ----------------
extern "C" void kernel_launch(void* const* d_in, const int* in_sizes, int n_in,
                              void* d_out, int out_size, void* d_ws, size_t ws_size,
                              hipStream_t stream) {
    const float* x     = (const float*)d_in[0];
    const float* mask  = (const float*)d_in[1];
    const float* polar = (const float*)d_in[2];
    const float* vote  = (const float*)d_in[3];
    const float* g1    = (const float*)d_in[4];
    const float* be1   = (const float*)d_in[5];
    const float* wqkv  = (const float*)d_in[6];
    const float* bqkv  = (const float*)d_in[7];
    const float* wproj = (const float*)d_in[8];
    const float* bproj = (const float*)d_in[9];
    const float* tau   = (const float*)d_in[10];
    const float* rw1   = (const float*)d_in[11];
    const float* rb1   = (const float*)d_in[12];
    const float* rw2   = (const float*)d_in[13];
    const float* rb2   = (const float*)d_in[14];
    const float* vw1   = (const float*)d_in[15];
    const float* vb1   = (const float*)d_in[16];
    const float* vw2   = (const float*)d_in[17];
    const float* vb2   = (const float*)d_in[18];
    const float* g2    = (const float*)d_in[19];
    const float* be2   = (const float*)d_in[20];
    const float* fc1w  = (const float*)d_in[21];
    const float* fc1b  = (const float*)d_in[22];
    const float* fc2w  = (const float*)d_in[23];
    const float* fc2b  = (const float*)d_in[24];
    float* out = (float*)d_out;

    // workspace (bytes), max offset 130,826,240 (~124.8 MiB):
    //   qkv    [0, 77,070,336)            bf16 [M][768]  dead after attn
    //   R2     [77,070,336, 102,760,448)  vemb -> attnout (sequential lives)
    //   hbuf   [0, 102,760,448)           bf16 [M][1024] overlays qkv+R2
    //   weights[102,760,448, 104,333,312) bf16
    //   lnbuf  [105,136,128, 130,826,240) bf16 [M][256]: xw then x2n
    char* base = (char*)d_ws;
    bf16*  qkv     = (bf16*)base;
    bf16*  vemb    = (bf16*)(base + 77070336);
    bf16*  attnout = (bf16*)(base + 77070336);
    bf16*  hbuf    = (bf16*)base;
    bf16*  wqkvb   = (bf16*)(base + 102760448);
    bf16*  wprojb  = wqkvb + 768 * 256;
    bf16*  fc1wb   = wprojb + 256 * 256;
    bf16*  fc2wb   = fc1wb + 1024 * 256;
    bf16*  lnbuf   = (bf16*)(base + 105136128);

    cvt_w<<<192, 256, 0, stream>>>(wqkv, wqkvb, 768*256/4);
    cvt_w<<<64,  256, 0, stream>>>(wproj, wprojb, 256*256/4);
    cvt_w<<<256, 256, 0, stream>>>(fc1w, fc1wb, 1024*256/4);
    cvt_w<<<256, 256, 0, stream>>>(fc2w, fc2wb, 256*1024/4);

    prep_ln<<<M / 4, 256, 0, stream>>>(x, g1, be1, lnbuf, 1);       // xw
    vemb_kernel<<<M / 64, 256, 0, stream>>>(vote, vw1, vb1, vw2, vb2, vemb);

    mfma_gemm<MODE_QKV, 6><<<(M / 256) * 6, 512, 0, stream>>>(
        lnbuf, wqkvb, bqkv, vemb, nullptr, qkv);

    attn_kernel<<<BT, 256, 0, stream>>>(qkv, polar, rw1, rb1, rw2, rb2, tau, mask, attnout);

    mfma_gemm<MODE_PROJ, 2><<<(M / 256) * 2, 512, 0, stream>>>(
        attnout, wprojb, bproj, nullptr, x, out);

    prep_ln<<<M / 4, 256, 0, stream>>>(out, g2, be2, lnbuf, 0);     // x2n

    mfma_gemm<MODE_FC1, 8><<<(M / 256) * 8, 512, 0, stream>>>(
        lnbuf, fc1wb, fc1b, nullptr, nullptr, hbuf);

    mfma_gemm<MODE_FC2, 2><<<(M / 256) * 2, 512, 0, stream>>>(
        hbuf, fc2wb, fc2b, nullptr, out, out);
}

// Round 22
// 302.976 us; speedup vs baseline: 1.2148x; 1.0054x over previous
//
#include <hip/hip_runtime.h>
#include <hip/hip_bf16.h>
#include <math.h>

using bf16 = __hip_bfloat16;
typedef __attribute__((ext_vector_type(8))) short short8;
typedef __attribute__((ext_vector_type(4))) float f32x4;
typedef unsigned int u32;

// ---------------- problem constants ----------------
constexpr int BB    = 4;
constexpr int Hh    = 112;
constexpr int Ww    = 112;
constexpr int C     = 256;
constexpr int L     = Hh * Ww;        // 12544
constexpr int HEADS = 8;
constexpr int WS    = 7;
constexpr int SHIFT = 3;
constexpr int HID   = 1024;
constexpr int HD    = 32;
constexpr int NWIN  = 49;
constexpr int NW    = 256;
constexpr int BT    = BB * NW;        // 1024 windows
constexpr int M     = BT * NWIN;      // 50176 tokens
constexpr float SCALE = 0.17677669529663687f;
constexpr float EPS   = 1e-5f;

// window-token r -> natural token index. Same map for gather and scatter.
__device__ __forceinline__ int src_row_idx(int r) {
    int b_ = r / NWIN;
    int n  = r - b_ * NWIN;
    int b  = b_ >> 8;
    int w  = b_ & 255;
    int wh = w >> 4, ww = w & 15;
    int i  = n / WS, j = n - i * WS;
    int hp = wh * WS + i, wp = ww * WS + j;
    int h  = hp + SHIFT; if (h >= Hh) h -= Hh;
    int wc = wp + SHIFT; if (wc >= Ww) wc -= Ww;
    return b * L + h * Ww + wc;
}

__device__ __forceinline__ float bf2f(short s) {
    u32 u = ((u32)(unsigned short)s) << 16;
    float f; __builtin_memcpy(&f, &u, 4); return f;
}
__device__ __forceinline__ short f2bfbits(float f) {
    bf16 b = __float2bfloat16(f);
    short s; __builtin_memcpy(&s, &b, 2); return s;
}
__device__ __forceinline__ u32 pack2bf(float lo, float hi) {
    return (u32)(unsigned short)f2bfbits(lo) | ((u32)(unsigned short)f2bfbits(hi) << 16);
}

#define GL2LDS(g, l) __builtin_amdgcn_global_load_lds( \
    (const __attribute__((address_space(1))) u32*)(const void*)(g), \
    (__attribute__((address_space(3))) u32*)(void*)(l), 16, 0, 0)

// ---------------- fused LN (+optional gather) -> bf16 ----------------
__global__ __launch_bounds__(256)
void prep_ln(const float* __restrict__ x, const float* __restrict__ g,
             const float* __restrict__ b, bf16* __restrict__ o, int gather) {
    int wave = threadIdx.x >> 6, lane = threadIdx.x & 63;
    int tok = blockIdx.x * 4 + wave;
    int srow = gather ? src_row_idx(tok) : tok;
    float4 v = *(const float4*)&x[(size_t)srow * C + lane * 4];
    float s  = v.x + v.y + v.z + v.w;
    float s2 = v.x*v.x + v.y*v.y + v.z*v.z + v.w*v.w;
    #pragma unroll
    for (int ofs = 32; ofs > 0; ofs >>= 1) {
        s  += __shfl_xor(s, ofs);
        s2 += __shfl_xor(s2, ofs);
    }
    float m    = s * (1.f / C);
    float rstd = rsqrtf(s2 * (1.f / C) - m * m + EPS);
    float4 gv = *(const float4*)&g[lane * 4];
    float4 bv = *(const float4*)&b[lane * 4];
    uint2 u;
    u.x = pack2bf((v.x - m) * rstd * gv.x + bv.x, (v.y - m) * rstd * gv.y + bv.y);
    u.y = pack2bf((v.z - m) * rstd * gv.z + bv.z, (v.w - m) * rstd * gv.w + bv.w);
    *(uint2*)&o[(size_t)tok * C + lane * 4] = u;
}

// ---------------- f32 -> bf16 weight convert ----------------
__global__ __launch_bounds__(256)
void cvt_w(const float* __restrict__ in, bf16* __restrict__ o, int n4) {
    int i = blockIdx.x * 256 + threadIdx.x;
    if (i >= n4) return;
    float4 v = *(const float4*)&in[(size_t)i * 4];
    bf16 t4[4] = {__float2bfloat16(v.x), __float2bfloat16(v.y),
                  __float2bfloat16(v.z), __float2bfloat16(v.w)};
    *(uint2*)&o[(size_t)i * 4] = *(const uint2*)t4;
}

// ---------------- vote-embed MLP: wave-per-token, coalesced writes ----------
__global__ __launch_bounds__(256)
void vemb_kernel(const float* __restrict__ vote,
                 const float* __restrict__ w1, const float* __restrict__ b1,
                 const float* __restrict__ w2, const float* __restrict__ b2,
                 bf16* __restrict__ vemb) {
    __shared__ float w2t[16][256];     // transposed, 16 KB
    __shared__ float w1s[48], b1s[16];
    const int tid = threadIdx.x;
    {
        const float4* src = (const float4*)(w2 + tid * 16);
        float4 r0 = src[0], r1 = src[1], r2 = src[2], r3 = src[3];
        float rr[16] = {r0.x, r0.y, r0.z, r0.w, r1.x, r1.y, r1.z, r1.w,
                        r2.x, r2.y, r2.z, r2.w, r3.x, r3.y, r3.z, r3.w};
        #pragma unroll
        for (int o = 0; o < 16; ++o) w2t[o][tid] = rr[o];
        if (tid < 48) w1s[tid] = w1[tid];
        else if (tid < 64) b1s[tid - 48] = b1[tid - 48];
    }
    __syncthreads();

    const int wv = tid >> 6, l = tid & 63;
    const float4 bb = *(const float4*)&b2[l * 4];

    for (int it = 0; it < 16; ++it) {
        const int r = blockIdx.x * 64 + wv * 16 + it;
        const int srow = src_row_idx(r);
        const float v0 = vote[(size_t)srow * 3];
        const float v1 = vote[(size_t)srow * 3 + 1];
        const float v2 = vote[(size_t)srow * 3 + 2];
        float hid[16];
        #pragma unroll
        for (int o = 0; o < 16; ++o)
            hid[o] = fmaxf(fmaf(w1s[o*3], v0, fmaf(w1s[o*3+1], v1,
                           fmaf(w1s[o*3+2], v2, b1s[o]))), 0.f);
        float4 acc = bb;
        #pragma unroll
        for (int o = 0; o < 16; ++o) {
            float4 w = *(const float4*)&w2t[o][l * 4];
            acc.x = fmaf(hid[o], w.x, acc.x);
            acc.y = fmaf(hid[o], w.y, acc.y);
            acc.z = fmaf(hid[o], w.z, acc.z);
            acc.w = fmaf(hid[o], w.w, acc.w);
        }
        uint2 u;
        u.x = pack2bf(acc.x, acc.y);
        u.y = pack2bf(acc.z, acc.w);
        *(uint2*)&vemb[(size_t)r * 256 + l * 4] = u;
    }
}

// ---------------- MFMA GEMM: 256x128 tile, 8 waves, pure-DMA, XCD swizzle --
// BM=256, BN=128, BK=64. 512 thr = 8 waves (4x2 of 64x64). LDS: A 32KB +
// B 16KB = 48KB, [rows][64 bf16] byte^=((row&7)<<4) swizzled. Each r-chunk
// stages 64 rows (8 waves x 8 rows) -> global stride r*64 rows = r*128*K
// BYTES (the R19 bug was r*64*K bytes = 32 rows).
enum { MODE_QKV = 0, MODE_PROJ = 1, MODE_FC1 = 2, MODE_FC2 = 3 };

template <int MODE, int NT>
__global__ __launch_bounds__(512)
void mfma_gemm(const bf16* __restrict__ A, const bf16* __restrict__ Wb,
               const float* __restrict__ bias,
               const bf16* __restrict__ vemb, const float* __restrict__ resid,
               void* __restrict__ outp) {
    constexpr int K = (MODE == MODE_FC2) ? 1024 : 256;
    __shared__ __align__(16) char ldsA[32768];
    __shared__ __align__(16) char ldsB[16384];

    const int tid  = threadIdx.x;
    const int lane = tid & 63;
    const int wid  = tid >> 6;                // 0..7
    const int wr   = wid >> 1, wc = wid & 1;  // 4x2 wave grid
    const int lrow = lane & 15, lk = lane >> 4;

    const int cpx = gridDim.x >> 3;                   // nwg always %8==0
    const int lg  = (blockIdx.x & 7) * cpx + (blockIdx.x >> 3);
    const int bx  = lg / NT, by = lg % NT;
    const int mBase = bx * 256, nBase = by * 128;

    // staging: one wave per GL2LDS call writes 8 rows (1024B). lane -> row
    // lane>>3 within chunk, 16B piece lane&7, swizzle ((lane>>3)&7)<<4.
    const int sbyte = ((lane & 7) * 16) ^ ((lane >> 3) << 4);
    const char* aSrc = (const char*)(A  + (size_t)(mBase + wid * 8 + (lane >> 3)) * K) + sbyte;
    const char* bSrc = (const char*)(Wb + (size_t)(nBase + wid * 8 + (lane >> 3)) * K) + sbyte;

    f32x4 acc[4][4] = {};

    for (int t = 0; t < K / 64; ++t) {
        if (t) __syncthreads();
        const size_t kof = (size_t)t * 128;
        #pragma unroll
        for (int r = 0; r < 4; ++r)            // A: 4 chunks x 64 rows = 256
            GL2LDS(aSrc + (size_t)r * 128 * K + kof,
                   ldsA + (r * 8 + wid) * 1024);
        #pragma unroll
        for (int r = 0; r < 2; ++r)            // B: 2 chunks x 64 rows = 128
            GL2LDS(bSrc + (size_t)r * 128 * K + kof,
                   ldsB + (r * 8 + wid) * 1024);
        __syncthreads();
        const int sw = (lrow & 7) << 4;
        #pragma unroll
        for (int ks = 0; ks < 2; ++ks) {
            const int kbl = (ks * 64 + lk * 16) ^ sw;
            short8 af[4], bfr[4];
            #pragma unroll
            for (int q = 0; q < 4; ++q) {
                af[q]  = *(const short8*)(ldsA + (wr * 64 + q * 16 + lrow) * 128 + kbl);
                bfr[q] = *(const short8*)(ldsB + (wc * 64 + q * 16 + lrow) * 128 + kbl);
            }
            #pragma unroll
            for (int mi = 0; mi < 4; ++mi)
                #pragma unroll
                for (int ni = 0; ni < 4; ++ni)
                    acc[mi][ni] = __builtin_amdgcn_mfma_f32_16x16x32_bf16(
                        af[mi], bfr[ni], acc[mi][ni], 0, 0, 0);
        }
    }

    // epilogue: ni innermost -> stores covering one line are consecutive
    const int cB = nBase + wc * 64 + lrow;
    const int rB = mBase + wr * 64 + lk * 4;
    float bs[4];
    #pragma unroll
    for (int ni = 0; ni < 4; ++ni) bs[ni] = bias[cB + ni * 16];
    #pragma unroll
    for (int mi = 0; mi < 4; ++mi) {
        #pragma unroll
        for (int i = 0; i < 4; ++i) {
            const int r = rB + mi * 16 + i;
            const int dst = (MODE == MODE_PROJ) ? src_row_idx(r) : r;
            #pragma unroll
            for (int ni = 0; ni < 4; ++ni) {
                const int c = cB + ni * 16;
                float v = acc[mi][ni][i] + bs[ni];
                if constexpr (MODE == MODE_QKV) {
                    float ve = __bfloat162float(vemb[(size_t)r * 256 + (c & 255)]);
                    v += (c >= 512) ? 2.f * ve : ve;   // v-path carries qkv2 + 2*vemb
                    ((bf16*)outp)[(size_t)r * 768 + c] = __float2bfloat16(v);
                } else if constexpr (MODE == MODE_PROJ) {
                    ((float*)outp)[(size_t)dst * 256 + c] =
                        resid[(size_t)dst * 256 + c] + v;
                } else if constexpr (MODE == MODE_FC1) {
                    float gl = 0.5f * v * (1.f + erff(v * 0.70710678118f));
                    ((bf16*)outp)[(size_t)r * 1024 + c] = __float2bfloat16(gl);
                } else {  // FC2: final residual add, f32 out
                    ((float*)outp)[(size_t)r * 256 + c] =
                        resid[(size_t)r * 256 + c] + v;
                }
            }
        }
    }
}

// ---------------- attention v3: head-parallel, zero inner barriers ---------
__global__ __launch_bounds__(256)
void attn_kernel(const bf16* __restrict__ qkv, const float* __restrict__ polar,
                 const float* __restrict__ rw1, const float* __restrict__ rb1,
                 const float* __restrict__ rw2, const float* __restrict__ rb2,
                 const float* __restrict__ tau, const float* __restrict__ mask,
                 bf16* __restrict__ outp) {
    const int w  = blockIdx.x;
    const int wl = w & 255;
    const int t  = threadIdx.x;
    const int lane = t & 63, wid = t >> 6;
    const int l15 = lane & 15, q4 = lane >> 4;
    const size_t wbase = (size_t)w * NWIN;
    const short* qs = (const short*)qkv;

    __shared__ float pwx[NWIN], pwy[NWIN];
    __shared__ float rqn[8][64], rkn[8][64];
    __shared__ float cw1s[32], cb1s[16], cw2s[8][16], rb2s[8], scts[8];
    __shared__ short rpem[8][2401];

    if (t < 98) {
        int n = t >> 1, cix = t & 1;
        int srow = src_row_idx(w * NWIN + n);
        float v = polar[(size_t)srow * 2 + cix];
        if (cix) pwy[n] = v; else pwx[n] = v;
    }
    if (t >= 128 && t < 256) {
        int u = t - 128;
        if (u < 128) cw2s[u >> 4][u & 15] = rw2[u];
    }
    if (t < 32) cw1s[t] = rw1[t];
    else if (t < 48) cb1s[t - 32] = rb1[t - 32];
    else if (t < 56) rb2s[t - 48] = rb2[t - 48];
    else if (t < 64) scts[t - 56] = SCALE / fmaxf(tau[t - 56], 0.01f);

    for (int idx = t; idx < 8 * NWIN; idx += 256) {
        int h = idx / NWIN, n = idx - h * NWIN;
        const bf16* qp = qkv + (wbase + n) * 768 + h * 32;
        float sq = 0, sk = 0;
        #pragma unroll
        for (int c = 0; c < 4; ++c) {
            short8 qv = *(const short8*)(qp + c * 8);
            short8 kv = *(const short8*)(qp + 256 + c * 8);
            #pragma unroll
            for (int j = 0; j < 8; ++j) {
                float qf = bf2f(qv[j]); sq += qf * qf;
                float kf = bf2f(kv[j]); sk += kf * kf;
            }
        }
        rqn[h][n] = rsqrtf(sq);
        rkn[h][n] = rsqrtf(sk);
    }
    __syncthreads();

    for (int e = t; e < NWIN * NWIN; e += 256) {
        int n = e / NWIN, m = e - n * NWIN;
        float dx = pwx[n] - pwx[m], dy = pwy[n] - pwy[m];
        float hid[16];
        #pragma unroll
        for (int o = 0; o < 16; ++o)
            hid[o] = fmaxf(fmaf(cw1s[2*o], dx, fmaf(cw1s[2*o+1], dy, cb1s[o])), 0.f);
        float mv = mask[(size_t)wl * NWIN * NWIN + e];
        #pragma unroll
        for (int h = 0; h < 8; ++h) {
            float a = rb2s[h] + mv;
            #pragma unroll
            for (int o = 0; o < 16; ++o) a = fmaf(hid[o], cw2s[h][o], a);
            rpem[h][e] = f2bfbits(a);
        }
    }
    __syncthreads();

    const short8 z8 = {0,0,0,0,0,0,0,0};
    const int qa  = (q4 & 1) * 2;
    const int sel = q4 >> 1;

    for (int hh = 0; hh < 2; ++hh) {
        const int h = wid + hh * 4;
        const bf16* hbase = qkv + wbase * 768 + h * 32;
        const float sct = scts[h];

        short8 kf[4], qf[4];
        #pragma unroll
        for (int at = 0; at < 4; ++at) {
            int m = at * 16 + l15;
            kf[at] = (m < NWIN) ? *(const short8*)(hbase + (size_t)m * 768 + 256 + q4 * 8) : z8;
        }
        #pragma unroll
        for (int nt = 0; nt < 4; ++nt) {
            int n = nt * 16 + l15;
            qf[nt] = (n < NWIN) ? *(const short8*)(hbase + (size_t)n * 768 + q4 * 8) : z8;
        }
        short8 vb[2][2];
        #pragma unroll
        for (int ks = 0; ks < 2; ++ks)
            #pragma unroll
            for (int ct = 0; ct < 2; ++ct) {
                short tmp[8];
                #pragma unroll
                for (int j = 0; j < 8; ++j) {
                    int m = ks * 32 + q4 * 8 + j;
                    tmp[j] = (m < NWIN)
                        ? qs[(wbase + m) * 768 + 512 + h * 32 + ct * 16 + l15]
                        : (short)0;
                }
                __builtin_memcpy(&vb[ks][ct], tmp, 16);
            }

        u32 pw[4][4][2];
        const f32x4 zf = {0.f, 0.f, 0.f, 0.f};
        #pragma unroll
        for (int nt = 0; nt < 4; ++nt) {
            f32x4 sacc[4];
            #pragma unroll
            for (int at = 0; at < 4; ++at)
                sacc[at] = __builtin_amdgcn_mfma_f32_16x16x32_bf16(kf[at], qf[nt], zf, 0, 0, 0);
            const int n = nt * 16 + l15;
            const float rq = rqn[h][n];
            float pv[4][4];
            #pragma unroll
            for (int at = 0; at < 4; ++at)
                #pragma unroll
                for (int i = 0; i < 4; ++i) {
                    int m = at * 16 + q4 * 4 + i;
                    float val = -1e30f;
                    if (n < NWIN && m < NWIN) {
                        float rr = fminf(rq * rkn[h][m], 1e6f);
                        val = sacc[at][i] * sct * rr + bf2f(rpem[h][n * NWIN + m]);
                    }
                    pv[at][i] = val;
                }
            float mx = -1e30f;
            #pragma unroll
            for (int at = 0; at < 4; ++at)
                #pragma unroll
                for (int i = 0; i < 4; ++i) mx = fmaxf(mx, pv[at][i]);
            mx = fmaxf(mx, __shfl_xor(mx, 16));
            mx = fmaxf(mx, __shfl_xor(mx, 32));
            float sum = 0.f;
            #pragma unroll
            for (int at = 0; at < 4; ++at)
                #pragma unroll
                for (int i = 0; i < 4; ++i) {
                    float ev = __expf(pv[at][i] - mx);
                    pv[at][i] = ev; sum += ev;
                }
            sum += __shfl_xor(sum, 16);
            sum += __shfl_xor(sum, 32);
            const float inv = 1.0f / sum;
            #pragma unroll
            for (int at = 0; at < 4; ++at) {
                pw[nt][at][0] = pack2bf(pv[at][0] * inv, pv[at][1] * inv);
                pw[nt][at][1] = pack2bf(pv[at][2] * inv, pv[at][3] * inv);
            }
        }

        f32x4 o[4][2] = {};
        #pragma unroll
        for (int nt = 0; nt < 4; ++nt) {
            #pragma unroll
            for (int ks = 0; ks < 2; ++ks) {
                u32 wv[4];
                #pragma unroll
                for (int w_ = 0; w_ < 4; ++w_) {
                    int srcl = l15 + (qa + (w_ >> 1)) * 16;
                    u32 lo = (u32)__shfl((int)pw[nt][2 * ks][w_ & 1], srcl);
                    u32 hi = (u32)__shfl((int)pw[nt][2 * ks + 1][w_ & 1], srcl);
                    wv[w_] = sel ? hi : lo;
                }
                short8 pa;
                __builtin_memcpy(&pa, wv, 16);
                #pragma unroll
                for (int ct = 0; ct < 2; ++ct)
                    o[nt][ct] = __builtin_amdgcn_mfma_f32_16x16x32_bf16(pa, vb[ks][ct], o[nt][ct], 0, 0, 0);
            }
        }

        #pragma unroll
        for (int nt = 0; nt < 4; ++nt)
            #pragma unroll
            for (int ct = 0; ct < 2; ++ct)
                #pragma unroll
                for (int i = 0; i < 4; ++i) {
                    int n = nt * 16 + q4 * 4 + i;
                    if (n < NWIN)
                        outp[(wbase + n) * 256 + h * 32 + ct * 16 + l15] =
                            __float2bfloat16(o[nt][ct][i]);
                }
    }
}

// ---------------- launch ----------------
extern "C" void kernel_launch(void* const* d_in, const int* in_sizes, int n_in,
                              void* d_out, int out_size, void* d_ws, size_t ws_size,
                              hipStream_t stream) {
    const float* x     = (const float*)d_in[0];
    const float* mask  = (const float*)d_in[1];
    const float* polar = (const float*)d_in[2];
    const float* vote  = (const float*)d_in[3];
    const float* g1    = (const float*)d_in[4];
    const float* be1   = (const float*)d_in[5];
    const float* wqkv  = (const float*)d_in[6];
    const float* bqkv  = (const float*)d_in[7];
    const float* wproj = (const float*)d_in[8];
    const float* bproj = (const float*)d_in[9];
    const float* tau   = (const float*)d_in[10];
    const float* rw1   = (const float*)d_in[11];
    const float* rb1   = (const float*)d_in[12];
    const float* rw2   = (const float*)d_in[13];
    const float* rb2   = (const float*)d_in[14];
    const float* vw1   = (const float*)d_in[15];
    const float* vb1   = (const float*)d_in[16];
    const float* vw2   = (const float*)d_in[17];
    const float* vb2   = (const float*)d_in[18];
    const float* g2    = (const float*)d_in[19];
    const float* be2   = (const float*)d_in[20];
    const float* fc1w  = (const float*)d_in[21];
    const float* fc1b  = (const float*)d_in[22];
    const float* fc2w  = (const float*)d_in[23];
    const float* fc2b  = (const float*)d_in[24];
    float* out = (float*)d_out;

    // workspace (bytes), max offset 130,826,240 (~124.8 MiB):
    //   qkv    [0, 77,070,336)            bf16 [M][768]  dead after attn
    //   R2     [77,070,336, 102,760,448)  vemb -> attnout (sequential lives)
    //   hbuf   [0, 102,760,448)           bf16 [M][1024] overlays qkv+R2
    //   weights[102,760,448, 104,333,312) bf16
    //   lnbuf  [105,136,128, 130,826,240) bf16 [M][256]: xw then x2n
    char* base = (char*)d_ws;
    bf16*  qkv     = (bf16*)base;
    bf16*  vemb    = (bf16*)(base + 77070336);
    bf16*  attnout = (bf16*)(base + 77070336);
    bf16*  hbuf    = (bf16*)base;
    bf16*  wqkvb   = (bf16*)(base + 102760448);
    bf16*  wprojb  = wqkvb + 768 * 256;
    bf16*  fc1wb   = wprojb + 256 * 256;
    bf16*  fc2wb   = fc1wb + 1024 * 256;
    bf16*  lnbuf   = (bf16*)(base + 105136128);

    cvt_w<<<192, 256, 0, stream>>>(wqkv, wqkvb, 768*256/4);
    cvt_w<<<64,  256, 0, stream>>>(wproj, wprojb, 256*256/4);
    cvt_w<<<256, 256, 0, stream>>>(fc1w, fc1wb, 1024*256/4);
    cvt_w<<<256, 256, 0, stream>>>(fc2w, fc2wb, 256*1024/4);

    prep_ln<<<M / 4, 256, 0, stream>>>(x, g1, be1, lnbuf, 1);       // xw
    vemb_kernel<<<M / 64, 256, 0, stream>>>(vote, vw1, vb1, vw2, vb2, vemb);

    mfma_gemm<MODE_QKV, 6><<<(M / 256) * 6, 512, 0, stream>>>(
        lnbuf, wqkvb, bqkv, vemb, nullptr, qkv);

    attn_kernel<<<BT, 256, 0, stream>>>(qkv, polar, rw1, rb1, rw2, rb2, tau, mask, attnout);

    mfma_gemm<MODE_PROJ, 2><<<(M / 256) * 2, 512, 0, stream>>>(
        attnout, wprojb, bproj, nullptr, x, out);

    prep_ln<<<M / 4, 256, 0, stream>>>(out, g2, be2, lnbuf, 0);     // x2n

    mfma_gemm<MODE_FC1, 8><<<(M / 256) * 8, 512, 0, stream>>>(
        lnbuf, fc1wb, fc1b, nullptr, nullptr, hbuf);

    mfma_gemm<MODE_FC2, 2><<<(M / 256) * 2, 512, 0, stream>>>(
        hbuf, fc2wb, fc2b, nullptr, out, out);
}